// Round 3
// baseline (2063.121 us; speedup 1.0000x reference)
//
#include <hip/hip_runtime.h>
#include <stdint.h>

#define HID 512
#define BAT 256

typedef __attribute__((ext_vector_type(8)))  short short8;
typedef __attribute__((ext_vector_type(16))) float floatx16;

static __device__ __forceinline__ unsigned short f2bf(float f) {
  union { float f; uint32_t u; } v; v.f = f;
  uint32_t u = v.u + (((v.u >> 16) & 1u) + 0x7FFFu);   // round-to-nearest-even
  return (unsigned short)(u >> 16);
}
static __device__ __forceinline__ float bf2f(unsigned short h) {
  union { uint32_t u; float f; } v; v.u = ((uint32_t)h) << 16;
  return v.f;
}
static __device__ __forceinline__ float fast_tanh(float v) {
  float e = __expf(2.0f * v);
  return 1.0f - 2.0f / (e + 1.0f);
}

// K0: split Wl into hi/lo bf16 fragments, Wr into hi fragments, MFMA B-frag
// order per 32-col block: frag[(j*32+kc)*64 + lane][jj]; n = j*32+(l&31),
// k = kc*16+(l>>5)*8+jj. Also clears BOTH hpk parity planes (1MB) so the
// step-tag protocol in rk2 never sees a stale tag from a previous launch:
// cleared words carry tag 0, which is unambiguous at first use (see rk2).
extern "C" __global__ __launch_bounds__(64) void rk0_frag(
    const float* __restrict__ Wl, const float* __restrict__ Wr,
    unsigned short* __restrict__ wlhi, unsigned short* __restrict__ wllo,
    unsigned short* __restrict__ wrhi, uint32_t* __restrict__ hpk) {
  int blk = blockIdx.x, l = threadIdx.x;
  {
    uint4 z = {0u, 0u, 0u, 0u};
    uint4* hp = (uint4*)hpk;
    int gid = blk * 64 + l;          // 512*64 = 32768 threads x 32B = 1MB
    hp[gid * 2 + 0] = z;
    hp[gid * 2 + 1] = z;
  }
  int j = blk >> 5, kc = blk & 31;
  int n = j * 32 + (l & 31);
  int kb = kc * 16 + ((l >> 5) << 3);
  size_t ob = ((size_t)blk * 64 + l) * 8;
#pragma unroll
  for (int jj = 0; jj < 8; ++jj) {
    int k = kb + jj;
    float wl = Wl[(size_t)k * HID + n];
    unsigned short hi = f2bf(wl);
    wlhi[ob + jj] = hi;
    wllo[ob + jj] = f2bf(wl - bf2f(hi));
    wrhi[ob + jj] = f2bf(Wr[(size_t)k * HID + n]);
  }
}

// K1: Rf[kb] = emb[tok(kb)] @ (kb==0 ? Wl : Wr) (+ bias for kb>0), emb-hi x
// W-hi single MFMA, f32 storage (the precision-critical part is f32 storage).
// One WG per (i, z): emb A-frags gathered ONCE into regs, then looped over all
// 16 col-blocks.
extern "C" __global__ __launch_bounds__(256, 1) void rk1_pre(
    const int* __restrict__ tokens, const float* __restrict__ emb,
    const float* __restrict__ bias,
    const unsigned short* __restrict__ wlhi, const unsigned short* __restrict__ wrhi,
    float* __restrict__ Rf) {
  __shared__ uint4 ldsb[2048];  // 32KB: Wr-hi frags for current col-block j
  int i = blockIdx.x, z = blockIdx.y;
  int tid = threadIdx.x, w = tid >> 6, l = tid & 63;
  int kb = z * 4 + w;                      // 0..255
  int b = i * 32 + (l & 31);
  int t = (kb == 0) ? 0 : (2 * kb - 1);
  int tok = tokens[t * BAT + b];
  int koff = (l >> 5) << 3;
  const float* ar = emb + (size_t)tok * HID + koff;
  uint32_t af[32][4];                      // A-frags (hi) in 128 VGPRs
#pragma unroll
  for (int kc = 0; kc < 32; ++kc) {
    float4 a0 = *(const float4*)(ar + kc * 16);
    float4 a1 = *(const float4*)(ar + kc * 16 + 4);
    af[kc][0] = (uint32_t)f2bf(a0.x) | ((uint32_t)f2bf(a0.y) << 16);
    af[kc][1] = (uint32_t)f2bf(a0.z) | ((uint32_t)f2bf(a0.w) << 16);
    af[kc][2] = (uint32_t)f2bf(a1.x) | ((uint32_t)f2bf(a1.y) << 16);
    af[kc][3] = (uint32_t)f2bf(a1.z) | ((uint32_t)f2bf(a1.w) << 16);
  }
  for (int jb = 0; jb < 16; ++jb) {
    __syncthreads();   // protect previous iteration's LDS reads
    {
      const uint4* src = (const uint4*)wrhi + (size_t)jb * 2048;
#pragma unroll
      for (int it = 0; it < 8; ++it) ldsb[it * 256 + tid] = src[it * 256 + tid];
    }
    __syncthreads();
    floatx16 acc = {};
    if (kb == 0) {     // wave-uniform: the one kb==0 wave uses Wl straight from global
      const uint4* bglob = (const uint4*)wlhi + (size_t)jb * 2048;
#pragma unroll 8
      for (int kc = 0; kc < 32; ++kc) {
        uint4 a4; a4.x = af[kc][0]; a4.y = af[kc][1]; a4.z = af[kc][2]; a4.w = af[kc][3];
        uint4 b4 = bglob[kc * 64 + l];
        acc = __builtin_amdgcn_mfma_f32_32x32x16_bf16(
            __builtin_bit_cast(short8, a4), __builtin_bit_cast(short8, b4), acc, 0, 0, 0);
      }
    } else {
#pragma unroll 8
      for (int kc = 0; kc < 32; ++kc) {
        uint4 a4; a4.x = af[kc][0]; a4.y = af[kc][1]; a4.z = af[kc][2]; a4.w = af[kc][3];
        uint4 b4 = ldsb[kc * 64 + l];
        acc = __builtin_amdgcn_mfma_f32_32x32x16_bf16(
            __builtin_bit_cast(short8, a4), __builtin_bit_cast(short8, b4), acc, 0, 0, 0);
      }
    }
    int col = jb * 32 + (l & 31);
    float bvv = (kb == 0) ? 0.0f : bias[col];
    float* dst = Rf + (size_t)kb * 131072 + ((size_t)i * 16 + jb) * 1024 + (size_t)l * 16;
    float4 o0 = {acc[0] + bvv,  acc[1] + bvv,  acc[2] + bvv,  acc[3] + bvv};
    float4 o1 = {acc[4] + bvv,  acc[5] + bvv,  acc[6] + bvv,  acc[7] + bvv};
    float4 o2 = {acc[8] + bvv,  acc[9] + bvv,  acc[10] + bvv, acc[11] + bvv};
    float4 o3 = {acc[12] + bvv, acc[13] + bvv, acc[14] + bvv, acc[15] + bvv};
    ((float4*)dst)[0] = o0; ((float4*)dst)[1] = o1;
    ((float4*)dst)[2] = o2; ((float4*)dst)[3] = o3;
  }
}

// K2: persistent recurrence with SELF-VALIDATING DATA (no flags, no drains,
// no RMWs). Each packed h word = hi_bf16 | (lo_bf16<<16); the 2 LSBs of lo
// (u32 bits 16-17) are overwritten with the step tag s&3 (error ~2^-15 rel,
// far below bf16 rounding noise). Producers fire h stores and move on.
// Consumers poll the data: a group of loads is accepted only when EVERY word
// carries tag (s-1)&3 (AND/OR accumulation over tag bits + wave vote).
// Safety: a parity plane's successive occupants differ by 2 steps (tags
// differ by 2 mod 4 -> distinguishable); skew>=2 between group members is
// impossible (each step consumes all members' previous tiles); the cleared-0
// tag is unambiguous at first use and later shadowed by per-address coherence
// (the consumer verified the intervening step's tag on every word at s-2).
#define LOADG(g, A_)                                                               \
  do {                                                                             \
    _Pragma("unroll") for (int c_ = 0; c_ < 8; ++c_) {                             \
      const unsigned long long* p8_ =                                              \
          (const unsigned long long*)(hb + abase + ((g)*8 + c_) * 16);             \
      A_[c_ * 4 + 0] = __hip_atomic_load(p8_ + 0, __ATOMIC_RELAXED,                \
                                         __HIP_MEMORY_SCOPE_AGENT);                \
      A_[c_ * 4 + 1] = __hip_atomic_load(p8_ + 1, __ATOMIC_RELAXED,                \
                                         __HIP_MEMORY_SCOPE_AGENT);                \
      A_[c_ * 4 + 2] = __hip_atomic_load(p8_ + 2, __ATOMIC_RELAXED,                \
                                         __HIP_MEMORY_SCOPE_AGENT);                \
      A_[c_ * 4 + 3] = __hip_atomic_load(p8_ + 3, __ATOMIC_RELAXED,                \
                                         __HIP_MEMORY_SCOPE_AGENT);                \
    }                                                                              \
  } while (0)

// 1 if ANY lane holds ANY word whose tag bits != pat (wave-collective).
#define STALE(A_)                                                                  \
  ({                                                                               \
    unsigned long long a_ = ~0ull, o_ = 0ull;                                      \
    _Pragma("unroll") for (int c_ = 0; c_ < 32; ++c_) {                            \
      a_ &= A_[c_];                                                                \
      o_ |= A_[c_];                                                                \
    }                                                                              \
    int bad_ = ((a_ & TAGMSK) != pat) | ((o_ & TAGMSK) != pat);                    \
    __any(bad_);                                                                   \
  })

#define CONSUME(g, A_)                                                             \
  do {                                                                             \
    _Pragma("unroll") for (int c_ = 0; c_ < 8; ++c_) {                             \
      int kc_ = (g)*8 + c_;                                                        \
      uint32_t w0 = (uint32_t)A_[c_ * 4 + 0], w1 = (uint32_t)(A_[c_ * 4 + 0] >> 32); \
      uint32_t w2 = (uint32_t)A_[c_ * 4 + 1], w3 = (uint32_t)(A_[c_ * 4 + 1] >> 32); \
      uint32_t w4 = (uint32_t)A_[c_ * 4 + 2], w5 = (uint32_t)(A_[c_ * 4 + 2] >> 32); \
      uint32_t w6 = (uint32_t)A_[c_ * 4 + 3], w7 = (uint32_t)(A_[c_ * 4 + 3] >> 32); \
      uint4 ahw, alw;                                                              \
      ahw.x = __builtin_amdgcn_perm(w1, w0, 0x05040100u);                          \
      alw.x = __builtin_amdgcn_perm(w1, w0, 0x07060302u);                          \
      ahw.y = __builtin_amdgcn_perm(w3, w2, 0x05040100u);                          \
      alw.y = __builtin_amdgcn_perm(w3, w2, 0x07060302u);                          \
      ahw.z = __builtin_amdgcn_perm(w5, w4, 0x05040100u);                          \
      alw.z = __builtin_amdgcn_perm(w5, w4, 0x07060302u);                          \
      ahw.w = __builtin_amdgcn_perm(w7, w6, 0x05040100u);                          \
      alw.w = __builtin_amdgcn_perm(w7, w6, 0x07060302u);                          \
      short8 ah = __builtin_bit_cast(short8, ahw);                                 \
      short8 al = __builtin_bit_cast(short8, alw);                                 \
      short8 bh = __builtin_bit_cast(short8, lds[kc_ * 64 + l]);                   \
      short8 bl = __builtin_bit_cast(short8, lds[2048 + kc_ * 64 + l]);            \
      acc0 = __builtin_amdgcn_mfma_f32_32x32x16_bf16(ah, bh, acc0, 0, 0, 0);       \
      acc1 = __builtin_amdgcn_mfma_f32_32x32x16_bf16(ah, bl, acc1, 0, 0, 0);       \
      acc2 = __builtin_amdgcn_mfma_f32_32x32x16_bf16(al, bh, acc2, 0, 0, 0);       \
    }                                                                              \
  } while (0)

extern "C" __global__ __launch_bounds__(64, 1) void rk2_rec(
    const unsigned short* __restrict__ wlhi, const unsigned short* __restrict__ wllo,
    const float* __restrict__ Rf,
    uint32_t* hpk, float* __restrict__ out) {
  __shared__ uint4 lds[4096];  // 64KB: [0,2048) Wl-hi frags, [2048,4096) Wl-lo
  const unsigned long long TAGMSK = 0x0003000000030000ull;
  int idx = blockIdx.x;
  int i = idx & 7, j = idx >> 3;  // idx%8==i -> row-group spread across XCDs
  int l = threadIdx.x;
  {
    const uint4* sh = (const uint4*)wlhi + (size_t)j * 2048;
    const uint4* sl = (const uint4*)wllo + (size_t)j * 2048;
#pragma unroll 4
    for (int it = 0; it < 32; ++it) {
      lds[it * 64 + l] = sh[it * 64 + l];
      lds[2048 + it * 64 + l] = sl[it * 64 + l];
    }
  }
  __syncthreads();
  int col = j * 32 + (l & 31);
  int r4 = (l >> 5) << 2;
  int arow = i * 32 + (l & 31);
  int koff = (l >> 5) << 3;
  size_t fragbase = ((size_t)i * 16 + j) * 1024 + (size_t)l * 16;  // floats
  size_t abase = (size_t)arow * HID + koff;  // uint32 elements within a parity plane
  float x[16];

  // ---- step 1: h1 = tanh(R0 + R1), store with tag 1 ----
  {
    const float4* r0 = (const float4*)(Rf + fragbase);
    const float4* r1 = (const float4*)(Rf + (size_t)131072 + fragbase);
#pragma unroll
    for (int q = 0; q < 4; ++q) {
      float4 a = r0[q], b = r1[q];
      x[q * 4 + 0] = fast_tanh(a.x + b.x);
      x[q * 4 + 1] = fast_tanh(a.y + b.y);
      x[q * 4 + 2] = fast_tanh(a.z + b.z);
      x[q * 4 + 3] = fast_tanh(a.w + b.w);
    }
  }
  {
    uint32_t* dstp = hpk + (size_t)(BAT * HID);  // parity 1
    const uint32_t tagv = 1u << 16;
#pragma unroll
    for (int r = 0; r < 16; ++r) {
      int row = i * 32 + r4 + (r & 3) + ((r >> 2) << 3);
      unsigned short h = f2bf(x[r]);
      unsigned short lo = f2bf(x[r] - bf2f(h));
      uint32_t word = ((uint32_t)h | ((uint32_t)lo << 16)) & 0xFFFCFFFFu;
      __hip_atomic_store(dstp + (size_t)row * HID + col, word | tagv,
                         __ATOMIC_RELAXED, __HIP_MEMORY_SCOPE_AGENT);
    }
  }
  // no drain, no flag: the tag IS the publication.

  // ---- steps 2..255 ----
  for (int s = 2; s <= 255; ++s) {
    float rv[16];
    {  // prefetch R_s (plain loads, clean read-only data) — in flight during poll
      const float4* rp = (const float4*)(Rf + (size_t)s * 131072 + fragbase);
#pragma unroll
      for (int q = 0; q < 4; ++q) {
        float4 a = rp[q];
        rv[q * 4 + 0] = a.x; rv[q * 4 + 1] = a.y;
        rv[q * 4 + 2] = a.z; rv[q * 4 + 3] = a.w;
      }
    }
    const uint32_t* hb = hpk + (size_t)((s - 1) & 1) * (BAT * HID);
    const unsigned long long tg = (unsigned long long)((s - 1) & 3) << 16;
    const unsigned long long pat = tg | (tg << 32);
    unsigned long long Abuf[32], Bbuf[32];
    floatx16 acc0 = {}, acc1 = {}, acc2 = {};
    // group 0 absorbs the detection; groups 1-3 pipeline behind it and
    // almost always pass first try (producers store all words ~together).
    do { LOADG(0, Abuf); } while (STALE(Abuf));
    LOADG(1, Bbuf);
    CONSUME(0, Abuf);
    while (STALE(Bbuf)) { LOADG(1, Bbuf); }
    LOADG(2, Abuf);
    CONSUME(1, Bbuf);
    while (STALE(Abuf)) { LOADG(2, Abuf); }
    LOADG(3, Bbuf);
    CONSUME(2, Abuf);
    while (STALE(Bbuf)) { LOADG(3, Bbuf); }
    CONSUME(3, Bbuf);
#pragma unroll
    for (int r = 0; r < 16; ++r)
      x[r] = fast_tanh(acc0[r] + acc1[r] + acc2[r] + rv[r]);
    if (s < 255) {
      uint32_t* dstp = hpk + (size_t)(s & 1) * (BAT * HID);
      const uint32_t tagv = (uint32_t)(s & 3) << 16;
#pragma unroll
      for (int r = 0; r < 16; ++r) {
        int row = i * 32 + r4 + (r & 3) + ((r >> 2) << 3);
        unsigned short h = f2bf(x[r]);
        unsigned short lo = f2bf(x[r] - bf2f(h));
        uint32_t word = ((uint32_t)h | ((uint32_t)lo << 16)) & 0xFFFCFFFFu;
        __hip_atomic_store(dstp + (size_t)row * HID + col, word | tagv,
                           __ATOMIC_RELAXED, __HIP_MEMORY_SCOPE_AGENT);
      }
    } else {
#pragma unroll
      for (int r = 0; r < 16; ++r) {
        int row = i * 32 + r4 + (r & 3) + ((r >> 2) << 3);
        out[(size_t)row * HID + col] = x[r];
      }
    }
  }
}

extern "C" void kernel_launch(void* const* d_in, const int* in_sizes, int n_in,
                              void* d_out, int out_size, void* d_ws, size_t ws_size,
                              hipStream_t stream) {
  const int*   tokens = (const int*)d_in[0];
  const float* emb    = (const float*)d_in[1];
  const float* Wl     = (const float*)d_in[2];
  const float* Wr     = (const float*)d_in[3];
  const float* bias   = (const float*)d_in[4];
  float* out = (float*)d_out;
  char* ws = (char*)d_ws;
  const size_t HALF_MB = 1u << 19;
  unsigned short* wlhi = (unsigned short*)(ws + 0 * HALF_MB);
  unsigned short* wllo = (unsigned short*)(ws + 1 * HALF_MB);
  unsigned short* wrhi = (unsigned short*)(ws + 2 * HALF_MB);
  uint32_t*       hpk  = (uint32_t*)(ws + 3 * HALF_MB);  // 2 x 256x512 x u32 = 1MB
  float* Rf            = (float*)(ws + 6 * HALF_MB);     // 134MB f32

  hipLaunchKernelGGL(rk0_frag, dim3(512), dim3(64), 0, stream,
                     Wl, Wr, wlhi, wllo, wrhi, hpk);
  hipLaunchKernelGGL(rk1_pre, dim3(8, 64), dim3(256), 0, stream,
                     tokens, emb, bias, wlhi, wrhi, Rf);
  hipLaunchKernelGGL(rk2_rec, dim3(128), dim3(64), 0, stream,
                     wlhi, wllo, Rf, hpk, out);
}

// Round 7
// 1604.405 us; speedup vs baseline: 1.2859x; 1.2859x over previous
//
#include <hip/hip_runtime.h>
#include <stdint.h>

#define HID 512
#define BAT 256

typedef __attribute__((ext_vector_type(8)))  short short8;
typedef __attribute__((ext_vector_type(16))) float floatx16;

static __device__ __forceinline__ unsigned short f2bf(float f) {
  union { float f; uint32_t u; } v; v.f = f;
  uint32_t u = v.u + (((v.u >> 16) & 1u) + 0x7FFFu);   // round-to-nearest-even
  return (unsigned short)(u >> 16);
}
static __device__ __forceinline__ float bf2f(unsigned short h) {
  union { uint32_t u; float f; } v; v.u = ((uint32_t)h) << 16;
  return v.f;
}
static __device__ __forceinline__ float fast_tanh(float v) {
  float e = __expf(2.0f * v);
  return 1.0f - 2.0f / (e + 1.0f);
}

// K0: split Wl into hi/lo bf16 fragments, Wr into hi fragments, MFMA B-frag
// order per 32-col block: frag[(j*32+kc)*64 + lane][jj]; n = j*32+(l&31),
// k = kc*16+(l>>5)*8+jj. Also clears BOTH hpk parity planes (1MB) so the
// step-tag protocol never sees stale tags from a previous launch/replay.
extern "C" __global__ __launch_bounds__(64) void rk0_frag(
    const float* __restrict__ Wl, const float* __restrict__ Wr,
    unsigned short* __restrict__ wlhi, unsigned short* __restrict__ wllo,
    unsigned short* __restrict__ wrhi, uint32_t* __restrict__ hpk) {
  int blk = blockIdx.x, l = threadIdx.x;
  {
    uint4 z = {0u, 0u, 0u, 0u};
    uint4* hp = (uint4*)hpk;
    int gid = blk * 64 + l;          // 512*64 = 32768 threads x 32B = 1MB
    hp[gid * 2 + 0] = z;
    hp[gid * 2 + 1] = z;
  }
  int j = blk >> 5, kc = blk & 31;
  int n = j * 32 + (l & 31);
  int kb = kc * 16 + ((l >> 5) << 3);
  size_t ob = ((size_t)blk * 64 + l) * 8;
#pragma unroll
  for (int jj = 0; jj < 8; ++jj) {
    int k = kb + jj;
    float wl = Wl[(size_t)k * HID + n];
    unsigned short hi = f2bf(wl);
    wlhi[ob + jj] = hi;
    wllo[ob + jj] = f2bf(wl - bf2f(hi));
    wrhi[ob + jj] = f2bf(Wr[(size_t)k * HID + n]);
  }
}

// K1: Rf[kb] = emb[tok(kb)] @ (kb==0 ? Wl : Wr) (+ bias for kb>0).
// Rf tile layout is Q-MAJOR: float4 index [q*64 + lane] within each
// (kb, i, jb) 1024-float tile, so rk2's per-q read is a dense 1KB/instr
// wave access (16 sectors) instead of a 4KB-span strided one (64 sectors).
extern "C" __global__ __launch_bounds__(256, 1) void rk1_pre(
    const int* __restrict__ tokens, const float* __restrict__ emb,
    const float* __restrict__ bias,
    const unsigned short* __restrict__ wlhi, const unsigned short* __restrict__ wrhi,
    float* __restrict__ Rf) {
  __shared__ uint4 ldsb[2048];  // 32KB: Wr-hi frags for current col-block j
  int i = blockIdx.x, z = blockIdx.y;
  int tid = threadIdx.x, w = tid >> 6, l = tid & 63;
  int kb = z * 4 + w;                      // 0..255
  int b = i * 32 + (l & 31);
  int t = (kb == 0) ? 0 : (2 * kb - 1);
  int tok = tokens[t * BAT + b];
  int koff = (l >> 5) << 3;
  const float* ar = emb + (size_t)tok * HID + koff;
  uint32_t af[32][4];                      // A-frags (hi) in 128 VGPRs
#pragma unroll
  for (int kc = 0; kc < 32; ++kc) {
    float4 a0 = *(const float4*)(ar + kc * 16);
    float4 a1 = *(const float4*)(ar + kc * 16 + 4);
    af[kc][0] = (uint32_t)f2bf(a0.x) | ((uint32_t)f2bf(a0.y) << 16);
    af[kc][1] = (uint32_t)f2bf(a0.z) | ((uint32_t)f2bf(a0.w) << 16);
    af[kc][2] = (uint32_t)f2bf(a1.x) | ((uint32_t)f2bf(a1.y) << 16);
    af[kc][3] = (uint32_t)f2bf(a1.z) | ((uint32_t)f2bf(a1.w) << 16);
  }
  for (int jb = 0; jb < 16; ++jb) {
    __syncthreads();   // protect previous iteration's LDS reads
    {
      const uint4* src = (const uint4*)wrhi + (size_t)jb * 2048;
#pragma unroll
      for (int it = 0; it < 8; ++it) ldsb[it * 256 + tid] = src[it * 256 + tid];
    }
    __syncthreads();
    floatx16 acc = {};
    if (kb == 0) {     // wave-uniform: the one kb==0 wave uses Wl straight from global
      const uint4* bglob = (const uint4*)wlhi + (size_t)jb * 2048;
#pragma unroll 8
      for (int kc = 0; kc < 32; ++kc) {
        uint4 a4; a4.x = af[kc][0]; a4.y = af[kc][1]; a4.z = af[kc][2]; a4.w = af[kc][3];
        uint4 b4 = bglob[kc * 64 + l];
        acc = __builtin_amdgcn_mfma_f32_32x32x16_bf16(
            __builtin_bit_cast(short8, a4), __builtin_bit_cast(short8, b4), acc, 0, 0, 0);
      }
    } else {
#pragma unroll 8
      for (int kc = 0; kc < 32; ++kc) {
        uint4 a4; a4.x = af[kc][0]; a4.y = af[kc][1]; a4.z = af[kc][2]; a4.w = af[kc][3];
        uint4 b4 = ldsb[kc * 64 + l];
        acc = __builtin_amdgcn_mfma_f32_32x32x16_bf16(
            __builtin_bit_cast(short8, a4), __builtin_bit_cast(short8, b4), acc, 0, 0, 0);
      }
    }
    int col = jb * 32 + (l & 31);
    float bvv = (kb == 0) ? 0.0f : bias[col];
    float4* dst4 = (float4*)(Rf + (size_t)kb * 131072 + ((size_t)i * 16 + jb) * 1024);
    float4 o0 = {acc[0] + bvv,  acc[1] + bvv,  acc[2] + bvv,  acc[3] + bvv};
    float4 o1 = {acc[4] + bvv,  acc[5] + bvv,  acc[6] + bvv,  acc[7] + bvv};
    float4 o2 = {acc[8] + bvv,  acc[9] + bvv,  acc[10] + bvv, acc[11] + bvv};
    float4 o3 = {acc[12] + bvv, acc[13] + bvv, acc[14] + bvv, acc[15] + bvv};
    dst4[0 * 64 + l] = o0; dst4[1 * 64 + l] = o1;
    dst4[2 * 64 + l] = o2; dst4[3 * 64 + l] = o3;
  }
}

// K2: persistent recurrence, round-3's PROVEN protocol (agent-scope relaxed
// atomics through the MALL coherence point, self-validating step tags in
// bits 16-17 of each packed word) with the exchange re-laid out in MFMA
// A-FRAGMENT ORDER to kill the transaction explosion:
//   plane u64 index (i, kc, w, lane) = ((i*32+kc)*4 + w)*64 + lane
//   (kc = k>>4, w = (k>>1)&3, lane = (row&31) + 32*((k>>3)&1), u32 = k&1)
// Consumer lane l's A-frag u64 for (kc,w) sits at ... + l  -> every h load
// is a 64x8B CONSECUTIVE wave access (8 sectors/instr, was ~32-64).
// Producer (i,j) owns kc in {2j, 2j+1} = one contiguous 4KB block: the 16
// C-frag words are staged in LDS, then written with 8 coalesced agent
// stores. NOTE: staging readback is u32-TYPED (same type as the writes) +
// compiler fence — round 6 read it back through a u64* cast, which TBAA is
// free to reorder against the u32 writes -> stale tags published -> group
// deadlock. Safety arguments (tag cycling mod 4 with 2 planes, per-address
// coherence shadowing of the cleared state, skew<2) unchanged from round 3.
#define LOADA(g, A_)                                                               \
  do {                                                                             \
    _Pragma("unroll") for (int c_ = 0; c_ < 8; ++c_) {                             \
      const unsigned long long* p8_ = hb2 + (size_t)((g)*8 + c_) * 256 + l;        \
      A_[c_ * 4 + 0] = __hip_atomic_load(p8_ + 0,   __ATOMIC_RELAXED,              \
                                         __HIP_MEMORY_SCOPE_AGENT);                \
      A_[c_ * 4 + 1] = __hip_atomic_load(p8_ + 64,  __ATOMIC_RELAXED,              \
                                         __HIP_MEMORY_SCOPE_AGENT);                \
      A_[c_ * 4 + 2] = __hip_atomic_load(p8_ + 128, __ATOMIC_RELAXED,              \
                                         __HIP_MEMORY_SCOPE_AGENT);                \
      A_[c_ * 4 + 3] = __hip_atomic_load(p8_ + 192, __ATOMIC_RELAXED,              \
                                         __HIP_MEMORY_SCOPE_AGENT);                \
    }                                                                              \
  } while (0)

// 1 if ANY lane holds ANY word whose tag bits != pat (wave-collective).
#define STALE(A_)                                                                  \
  ({                                                                               \
    unsigned long long a_ = ~0ull, o_ = 0ull;                                      \
    _Pragma("unroll") for (int c_ = 0; c_ < 32; ++c_) {                            \
      a_ &= A_[c_];                                                                \
      o_ |= A_[c_];                                                                \
    }                                                                              \
    int bad_ = ((a_ & TAGMSK) != pat) | ((o_ & TAGMSK) != pat);                    \
    __any(bad_);                                                                   \
  })

#define CONSUME(g, A_)                                                             \
  do {                                                                             \
    _Pragma("unroll") for (int c_ = 0; c_ < 8; ++c_) {                             \
      int kc_ = (g)*8 + c_;                                                        \
      uint32_t w0 = (uint32_t)A_[c_ * 4 + 0], w1 = (uint32_t)(A_[c_ * 4 + 0] >> 32); \
      uint32_t w2 = (uint32_t)A_[c_ * 4 + 1], w3 = (uint32_t)(A_[c_ * 4 + 1] >> 32); \
      uint32_t w4 = (uint32_t)A_[c_ * 4 + 2], w5 = (uint32_t)(A_[c_ * 4 + 2] >> 32); \
      uint32_t w6 = (uint32_t)A_[c_ * 4 + 3], w7 = (uint32_t)(A_[c_ * 4 + 3] >> 32); \
      uint4 ahw, alw;                                                              \
      ahw.x = __builtin_amdgcn_perm(w1, w0, 0x05040100u);                          \
      alw.x = __builtin_amdgcn_perm(w1, w0, 0x07060302u);                          \
      ahw.y = __builtin_amdgcn_perm(w3, w2, 0x05040100u);                          \
      alw.y = __builtin_amdgcn_perm(w3, w2, 0x07060302u);                          \
      ahw.z = __builtin_amdgcn_perm(w5, w4, 0x05040100u);                          \
      alw.z = __builtin_amdgcn_perm(w5, w4, 0x07060302u);                          \
      ahw.w = __builtin_amdgcn_perm(w7, w6, 0x05040100u);                          \
      alw.w = __builtin_amdgcn_perm(w7, w6, 0x07060302u);                          \
      short8 ah = __builtin_bit_cast(short8, ahw);                                 \
      short8 al = __builtin_bit_cast(short8, alw);                                 \
      short8 bh = __builtin_bit_cast(short8, lds[kc_ * 64 + l]);                   \
      short8 bl = __builtin_bit_cast(short8, lds[2048 + kc_ * 64 + l]);            \
      acc0 = __builtin_amdgcn_mfma_f32_32x32x16_bf16(ah, bh, acc0, 0, 0, 0);       \
      acc1 = __builtin_amdgcn_mfma_f32_32x32x16_bf16(ah, bl, acc1, 0, 0, 0);       \
      acc2 = __builtin_amdgcn_mfma_f32_32x32x16_bf16(al, bh, acc2, 0, 0, 0);       \
    }                                                                              \
  } while (0)

// tag-stamped h tile store in frag order: LDS-stage the 16 scattered words
// (u32 writes), fence, read back as u32 PAIRS (same type -> dependence
// visible, no TBAA hazard), then 8 coalesced u64 agent stores into
// producer (i,j)'s contiguous 4KB block.
#define STOREH(dplane_u32_, tagv_)                                                 \
  do {                                                                             \
    _Pragma("unroll") for (int r = 0; r < 16; ++r) {                               \
      int rowm = r4 + (r & 3) + ((r >> 2) << 3);                                   \
      unsigned short h = f2bf(x[r]);                                               \
      unsigned short lo = f2bf(x[r] - bf2f(h));                                    \
      uint32_t word = (((uint32_t)h | ((uint32_t)lo << 16)) & 0xFFFCFFFFu) | (tagv_); \
      stg[sbase + rowm * 2] = word;                                                \
    }                                                                              \
    asm volatile("" ::: "memory");  /* staging writes ordered before readback */   \
    unsigned long long* dst8_ =                                                    \
        (unsigned long long*)(dplane_u32_) + (size_t)i * 8192 + (size_t)j * 512;   \
    _Pragma("unroll") for (int wi_ = 0; wi_ < 8; ++wi_) {                          \
      int si_ = (wi_ * 64 + l) * 2;                                                \
      unsigned long long v_ = (unsigned long long)stg[si_] |                       \
                              ((unsigned long long)stg[si_ + 1] << 32);            \
      __hip_atomic_store(dst8_ + wi_ * 64 + l, v_,                                 \
                         __ATOMIC_RELAXED, __HIP_MEMORY_SCOPE_AGENT);              \
    }                                                                              \
  } while (0)

extern "C" __global__ __launch_bounds__(64, 1) void rk2_rec(
    const unsigned short* __restrict__ wlhi, const unsigned short* __restrict__ wllo,
    const float* __restrict__ Rf,
    uint32_t* hpk, float* __restrict__ out) {
  __shared__ uint4 lds[4096];  // 64KB: [0,2048) Wl-hi frags, [2048,4096) Wl-lo
  __shared__ __align__(16) uint32_t stg[1024];  // 4KB frag-order staging
  const unsigned long long TAGMSK = 0x0003000000030000ull;
  int idx = blockIdx.x;
  int i = idx & 7, j = idx >> 3;  // idx%8==i -> row-group spread across XCDs
  int l = threadIdx.x;
  {
    const uint4* sh = (const uint4*)wlhi + (size_t)j * 2048;
    const uint4* sl = (const uint4*)wllo + (size_t)j * 2048;
#pragma unroll 4
    for (int it = 0; it < 32; ++it) {
      lds[it * 64 + l] = sh[it * 64 + l];
      lds[2048 + it * 64 + l] = sl[it * 64 + l];
    }
  }
  __syncthreads();
  int col = j * 32 + (l & 31);
  int r4 = (l >> 5) << 2;
  // staging base for this lane: frag-order u32 index = wblk*128 + khalf*64 +
  // rowm*2 + (k&1), with wblk = (k bit4)*4 + (k bits 2:1), khalf = k bit3,
  // and k = j*32 + (l&31)  ->  all bit fields come straight from l.
  int sbase = ((((l >> 4) & 1) * 4 + ((l >> 1) & 3)) * 128) +
              (((l >> 3) & 1) << 6) + (l & 1);
  size_t fragbase = ((size_t)i * 16 + j) * 1024;  // floats (q-major tile base)
  float x[16];

  // ---- step 1: h1 = tanh(R0 + R1), store with tag 1 ----
  {
    const float4* r0 = (const float4*)(Rf + fragbase);
    const float4* r1 = (const float4*)(Rf + (size_t)131072 + fragbase);
#pragma unroll
    for (int q = 0; q < 4; ++q) {
      float4 a = r0[q * 64 + l], b = r1[q * 64 + l];
      x[q * 4 + 0] = fast_tanh(a.x + b.x);
      x[q * 4 + 1] = fast_tanh(a.y + b.y);
      x[q * 4 + 2] = fast_tanh(a.z + b.z);
      x[q * 4 + 3] = fast_tanh(a.w + b.w);
    }
  }
  STOREH(hpk + (size_t)(BAT * HID), 1u << 16);  // parity 1
  // no drain, no flag: the tag IS the publication.

  // ---- steps 2..255 ----
  for (int s = 2; s <= 255; ++s) {
    float rv[16];
    {  // prefetch R_s (plain loads, clean read-only data) — in flight during poll
      const float4* rp = (const float4*)(Rf + (size_t)s * 131072 + fragbase);
#pragma unroll
      for (int q = 0; q < 4; ++q) {
        float4 a = rp[q * 64 + l];
        rv[q * 4 + 0] = a.x; rv[q * 4 + 1] = a.y;
        rv[q * 4 + 2] = a.z; rv[q * 4 + 3] = a.w;
      }
    }
    const unsigned long long* hb2 =
        (const unsigned long long*)(hpk + (size_t)((s - 1) & 1) * (BAT * HID)) +
        (size_t)i * 8192;
    const unsigned long long tg = (unsigned long long)((s - 1) & 3) << 16;
    const unsigned long long pat = tg | (tg << 32);
    unsigned long long Abuf[32], Bbuf[32];
    floatx16 acc0 = {}, acc1 = {}, acc2 = {};
    // group 0 absorbs the detection; groups 1-3 pipeline behind it and
    // almost always pass first try (producers store all words ~together).
    do { LOADA(0, Abuf); } while (STALE(Abuf));
    LOADA(1, Bbuf);
    CONSUME(0, Abuf);
    while (STALE(Bbuf)) { LOADA(1, Bbuf); }
    LOADA(2, Abuf);
    CONSUME(1, Bbuf);
    while (STALE(Abuf)) { LOADA(2, Abuf); }
    LOADA(3, Bbuf);
    CONSUME(2, Abuf);
    while (STALE(Bbuf)) { LOADA(3, Bbuf); }
    CONSUME(3, Bbuf);
#pragma unroll
    for (int r = 0; r < 16; ++r)
      x[r] = fast_tanh(acc0[r] + acc1[r] + acc2[r] + rv[r]);
    if (s < 255) {
      STOREH(hpk + (size_t)(s & 1) * (BAT * HID), (uint32_t)(s & 3) << 16);
    } else {
#pragma unroll
      for (int r = 0; r < 16; ++r) {
        int row = i * 32 + r4 + (r & 3) + ((r >> 2) << 3);
        out[(size_t)row * HID + col] = x[r];
      }
    }
  }
}

extern "C" void kernel_launch(void* const* d_in, const int* in_sizes, int n_in,
                              void* d_out, int out_size, void* d_ws, size_t ws_size,
                              hipStream_t stream) {
  const int*   tokens = (const int*)d_in[0];
  const float* emb    = (const float*)d_in[1];
  const float* Wl     = (const float*)d_in[2];
  const float* Wr     = (const float*)d_in[3];
  const float* bias   = (const float*)d_in[4];
  float* out = (float*)d_out;
  char* ws = (char*)d_ws;
  const size_t HALF_MB = 1u << 19;
  unsigned short* wlhi = (unsigned short*)(ws + 0 * HALF_MB);
  unsigned short* wllo = (unsigned short*)(ws + 1 * HALF_MB);
  unsigned short* wrhi = (unsigned short*)(ws + 2 * HALF_MB);
  uint32_t*       hpk  = (uint32_t*)(ws + 3 * HALF_MB);  // 2 x 256x512 x u32 = 1MB
  float* Rf            = (float*)(ws + 6 * HALF_MB);     // 134MB f32

  hipLaunchKernelGGL(rk0_frag, dim3(512), dim3(64), 0, stream,
                     Wl, Wr, wlhi, wllo, wrhi, hpk);
  hipLaunchKernelGGL(rk1_pre, dim3(8, 64), dim3(256), 0, stream,
                     tokens, emb, bias, wlhi, wrhi, Rf);
  hipLaunchKernelGGL(rk2_rec, dim3(128), dim3(64), 0, stream,
                     wlhi, wllo, Rf, hpk, out);
}